// Round 5
// baseline (317.824 us; speedup 1.0000x reference)
//
#include <hip/hip_runtime.h>
#include <hip/hip_bf16.h>

// WhaleAttention: B=2, N=2048, C=1024, H=16, D=64, SCALE=1/8
// R5: prefetch double-buffering in attn + GEMM K-loops (hide global_load_lds
// latency behind compute across the barrier); all 7 casts merged into one
// dispatch. Algorithm unchanged from R4 (kp=k+p, c-init, fixed-base exp2).

typedef short bf16x8 __attribute__((ext_vector_type(8)));
typedef float f32x4 __attribute__((ext_vector_type(4)));

#define BB 2
#define NN 2048
#define CC 1024
#define HH 16
#define DD 64
#define MM (BB * NN)      // 4096 rows
#define SC2E 0.18033688f  // SCALE * log2(e)

__device__ __forceinline__ unsigned short f2bf(float f) {
    union { float f; unsigned int u; } x; x.f = f;
    unsigned int r = x.u + 0x7FFFu + ((x.u >> 16) & 1u);
    return (unsigned short)(r >> 16);
}

__device__ __forceinline__ float bf2f(unsigned short s) {
    union { unsigned int u; float f; } x; x.u = ((unsigned int)s) << 16;
    return x.f;
}

// packed f32x2 -> bf16x2 (v_cvt_pk_bf16_f32), low short = a
__device__ __forceinline__ unsigned int pk2(float a, float b) {
    __hip_bfloat162 h = __float22bfloat162_rn(make_float2(a, b));
    unsigned int u; __builtin_memcpy(&u, &h, 4); return u;
}

typedef __attribute__((address_space(1))) const unsigned int* gas1_t;
typedef __attribute__((address_space(3))) unsigned int* las3_t;

__device__ __forceinline__ void gload_lds16(const unsigned short* g, unsigned short* l) {
    __builtin_amdgcn_global_load_lds((gas1_t)g, (las3_t)l, 16, 0, 0);
}

// ---------------------------------------------------------------- cast kernel
// One dispatch for all 7 tensors: grid (4096, 7); y = tensor id.
struct CastArgs {
    const float* src[7];
    unsigned short* dst[7];
    int n4[7];
};
__global__ __launch_bounds__(256) void cast_all(CastArgs a) {
    const int seg = blockIdx.y;
    const int i = blockIdx.x * 256 + threadIdx.x;
    if (i >= a.n4[seg]) return;
    float4 v = ((const float4*)a.src[seg])[i];
    uint2 u;
    u.x = pk2(v.x, v.y);
    u.y = pk2(v.z, v.w);
    ((uint2*)a.dst[seg])[i] = u;
}

// ---------------------------------------------------------------- GEMM (BT)
// C[m][n] = sum_k A[m][k] * B[n][k];  tiles 128x64, BK=32, prefetch dbuf.
// MODE 0: out0 bf16 = acc + bias
// MODE 1: out0 bf16 = (acc + bias) * SC2E          (scaled q)
// MODE 2: out0 fp32 = acc + bias
// MODE 3: out0 bf16 transposed (B,H,D,N)
// MODE 4: out0 bf16 = acc + aux[row][col]          (kp = p + k)
template <int MODE>
__global__ __launch_bounds__(256) void gemm_bt(const unsigned short* __restrict__ A,
                                               const unsigned short* __restrict__ B,
                                               void* __restrict__ out0,
                                               const void* __restrict__ aux,
                                               const float* __restrict__ bias) {
    constexpr int K = CC;
    __shared__ unsigned short As[2][128 * 32];
    __shared__ unsigned short Bs[2][64 * 32];
    const int t = threadIdx.x;
    const int w = t >> 6, lane = t & 63, l15 = lane & 15, quad = lane >> 4;
    const int m0 = blockIdx.x * 128, n0 = blockIdx.y * 64;
    const int wm = (w >> 1) * 64, wn = (w & 1) * 32;

    // per-thread staging coords (loop-invariant)
    const int ar0 = t >> 2, ac = (t & 3) * 8;          // A chunk 0: rows 0..63
    const int ar1 = 64 + ar0;                          // A chunk 1: rows 64..127
    const int br = t >> 2, bc = (t & 3) * 8;           // B chunk

    f32x4 acc[4][2];
#pragma unroll
    for (int i = 0; i < 4; ++i)
#pragma unroll
        for (int j = 0; j < 2; ++j)
#pragma unroll
            for (int r = 0; r < 4; ++r) acc[i][j][r] = 0.f;

    // preload kb=0 into buf 0
    gload_lds16(&A[(size_t)(m0 + ar0) * K + ac], &As[0][t * 8]);
    gload_lds16(&A[(size_t)(m0 + ar1) * K + ac], &As[0][(256 + t) * 8]);
    gload_lds16(&B[(size_t)(n0 + br) * K + bc], &Bs[0][t * 8]);

    for (int kb = 0; kb < K / 32; ++kb) {
        __syncthreads();                       // buf[kb&1] ready (vmcnt drain)
        const int cur = kb & 1;
        if (kb + 1 < K / 32) {                 // prefetch next into other buf
            const int nb = cur ^ 1, ko = (kb + 1) * 32;
            gload_lds16(&A[(size_t)(m0 + ar0) * K + ko + ac], &As[nb][t * 8]);
            gload_lds16(&A[(size_t)(m0 + ar1) * K + ko + ac], &As[nb][(256 + t) * 8]);
            gload_lds16(&B[(size_t)(n0 + br) * K + ko + bc], &Bs[nb][t * 8]);
        }
        bf16x8 af[4], bfr[2];
#pragma unroll
        for (int i = 0; i < 4; ++i)
            af[i] = *(const bf16x8*)&As[cur][(wm + i * 16 + l15) * 32 + quad * 8];
#pragma unroll
        for (int j = 0; j < 2; ++j)
            bfr[j] = *(const bf16x8*)&Bs[cur][(wn + j * 16 + l15) * 32 + quad * 8];
#pragma unroll
        for (int i = 0; i < 4; ++i)
#pragma unroll
            for (int j = 0; j < 2; ++j)
                acc[i][j] = __builtin_amdgcn_mfma_f32_16x16x32_bf16(af[i], bfr[j], acc[i][j], 0, 0, 0);
    }

    // epilogue: C/D layout col = lane&15, row = quad*4 + reg
#pragma unroll
    for (int i = 0; i < 4; ++i) {
#pragma unroll
        for (int j = 0; j < 2; ++j) {
            const int col = n0 + wn + j * 16 + l15;
            const int row_base = m0 + wm + i * 16 + quad * 4;
            const float bc2 = (MODE == 4) ? 0.f : (bias ? bias[col] : 0.f);
            if (MODE == 0) {
#pragma unroll
                for (int r = 0; r < 4; ++r)
                    ((unsigned short*)out0)[(size_t)(row_base + r) * CC + col] = f2bf(acc[i][j][r] + bc2);
            } else if (MODE == 1) {
#pragma unroll
                for (int r = 0; r < 4; ++r)
                    ((unsigned short*)out0)[(size_t)(row_base + r) * CC + col] =
                        f2bf((acc[i][j][r] + bc2) * SC2E);
            } else if (MODE == 2) {
#pragma unroll
                for (int r = 0; r < 4; ++r)
                    ((float*)out0)[(size_t)(row_base + r) * CC + col] = acc[i][j][r] + bc2;
            } else if (MODE == 4) {
#pragma unroll
                for (int r = 0; r < 4; ++r) {
                    float kv = bf2f(((const unsigned short*)aux)[(size_t)(row_base + r) * CC + col]);
                    ((unsigned short*)out0)[(size_t)(row_base + r) * CC + col] = f2bf(acc[i][j][r] + kv);
                }
            } else {  // MODE 3: transposed V write
                const int b = row_base >> 11, nseq = row_base & 2047;
                const int hh = col >> 6, dd = col & 63;
                union { unsigned short s[4]; uint2 u; } pk;
#pragma unroll
                for (int r = 0; r < 4; ++r) pk.s[r] = f2bf(acc[i][j][r] + bc2);
                size_t idx = ((size_t)(b * HH + hh) * DD + dd) * NN + nseq;
                *(uint2*)&((unsigned short*)out0)[idx] = pk.u;
            }
        }
    }
}

// ---------------------------------------------------------------- c kernel
// c[b][h][n] = SC2E * sum_d ( (u-v)[h][d]*k + v[h][d]*kp ),  kp = k + p
__global__ __launch_bounds__(256) void fuse_c(const unsigned short* __restrict__ k,
                                              const unsigned short* __restrict__ kp,
                                              const float* __restrict__ pbu,
                                              const float* __restrict__ pbv,
                                              float* __restrict__ c) {
    const int gw = (blockIdx.x * 256 + threadIdx.x) >> 6;
    const int lane = threadIdx.x & 63;
    const int row = gw >> 4, h = gw & 15;          // row = b*N + n
    const size_t off = (size_t)row * CC + h * 64 + lane;
    const float u = pbu[h * 64 + lane], v = pbv[h * 64 + lane];
    float val = (u - v) * bf2f(k[off]) + v * bf2f(kp[off]);
#pragma unroll
    for (int o = 1; o < 64; o <<= 1) val += __shfl_xor(val, o);
    if (lane == 0) {
        const int b = row >> 11, n = row & 2047;
        c[((size_t)(b * HH + h)) * NN + n] = val * SC2E;
    }
}

// ---------------------------------------------------------------- attention
// Block: (qt,h,b) -> 128 Q rows; 4 waves x 32 Q. Transposed orientation:
//   S^T[key][q] = KP·Q^T, accumulator initialized with c[key]
//   P = exp2(S) (fixed base), P -> per-wave LDS -> B-frags
//   O^T[d][q] = V^T·P; final O /= l. Prefetch-dbuf K/V tiles (1 barrier/iter).
#define PST 80
__global__ __launch_bounds__(256, 2) void attn_kernel(const unsigned short* __restrict__ q,
                                                      const unsigned short* __restrict__ kp,
                                                      const unsigned short* __restrict__ vt,
                                                      const float* __restrict__ cb,
                                                      unsigned short* __restrict__ att) {
    __shared__ unsigned short Ks[2][64 * 64];
    __shared__ unsigned short Vs[2][64 * 64];
    __shared__ unsigned short Ps[4][32 * PST];

    const int t = threadIdx.x;
    const int w = t >> 6, lane = t & 63, l15 = lane & 15, quad = lane >> 4;
    const int qt = blockIdx.x, h = blockIdx.y, b = blockIdx.z;
    const int sw = (l15 & 7) * 8;

    const size_t kbase = (size_t)b * NN * CC + (size_t)h * DD;
    const size_t vbase = (size_t)(b * HH + h) * DD * NN;
    const size_t cbase = (size_t)(b * HH + h) * NN;

    // staging coords (loop-invariant): 2 chunks/thread per tile
    const int sr0 = t >> 3, sc0 = ((t & 7) ^ (sr0 & 7)) * 8;       // rows 0..31
    const int sr1 = 32 + (t >> 3), sc1 = ((t & 7) ^ (sr1 & 7)) * 8; // rows 32..63

    bf16x8 qf[2][2];
#pragma unroll
    for (int qb = 0; qb < 2; ++qb) {
        const int qrow = qt * 128 + w * 32 + qb * 16 + l15;
        const size_t qoff = ((size_t)(b * NN + qrow) * HH + h) * DD;
#pragma unroll
        for (int c2 = 0; c2 < 2; ++c2)
            qf[qb][c2] = *(const bf16x8*)&q[qoff + c2 * 32 + quad * 8];
    }

    f32x4 oT[4][2];
    float l_lane[2] = {0.f, 0.f};
#pragma unroll
    for (int db = 0; db < 4; ++db)
#pragma unroll
        for (int qb = 0; qb < 2; ++qb)
#pragma unroll
            for (int r = 0; r < 4; ++r) oT[db][qb][r] = 0.f;

    // preload kt=0 into buf 0
    gload_lds16(&kp[kbase + (size_t)sr0 * CC + sc0], &Ks[0][t * 8]);
    gload_lds16(&kp[kbase + (size_t)sr1 * CC + sc1], &Ks[0][(256 + t) * 8]);
    gload_lds16(&vt[vbase + (size_t)sr0 * NN + sc0], &Vs[0][t * 8]);
    gload_lds16(&vt[vbase + (size_t)sr1 * NN + sc1], &Vs[0][(256 + t) * 8]);

    for (int kt = 0; kt < NN / 64; ++kt) {
        __syncthreads();                        // buf[kt&1] ready
        const int cur = kt & 1;
        if (kt + 1 < NN / 64) {                 // prefetch next tile
            const int nb = cur ^ 1;
            const size_t ko = (size_t)(kt + 1) * 64;
            gload_lds16(&kp[kbase + (ko + sr0) * CC + sc0], &Ks[nb][t * 8]);
            gload_lds16(&kp[kbase + (ko + sr1) * CC + sc1], &Ks[nb][(256 + t) * 8]);
            gload_lds16(&vt[vbase + (size_t)sr0 * NN + ko + sc0], &Vs[nb][t * 8]);
            gload_lds16(&vt[vbase + (size_t)sr1 * NN + ko + sc1], &Vs[nb][(256 + t) * 8]);
        }

        // S^T with c-initialized accumulators
        f32x4 s[2][4];
#pragma unroll
        for (int t4 = 0; t4 < 4; ++t4) {
            f32x4 c4 = *(const f32x4*)&cb[cbase + kt * 64 + t4 * 16 + quad * 4];
            s[0][t4] = c4; s[1][t4] = c4;
        }
#pragma unroll
        for (int t4 = 0; t4 < 4; ++t4) {
            const int row = t4 * 16 + l15;
#pragma unroll
            for (int c2 = 0; c2 < 2; ++c2) {
                bf16x8 kf = *(const bf16x8*)&Ks[cur][row * 64 + ((c2 * 4 + quad) * 8 ^ sw)];
#pragma unroll
                for (int qb = 0; qb < 2; ++qb)
                    s[qb][t4] = __builtin_amdgcn_mfma_f32_16x16x32_bf16(kf, qf[qb][c2], s[qb][t4], 0, 0, 0);
            }
        }

        // fixed-base exp2 softmax; l reduced at end of kernel
#pragma unroll
        for (int qb = 0; qb < 2; ++qb) {
            float rs = 0.f;
#pragma unroll
            for (int t4 = 0; t4 < 4; ++t4)
#pragma unroll
                for (int r = 0; r < 4; ++r) {
                    float pv = exp2f(s[qb][t4][r]);
                    s[qb][t4][r] = pv;
                    rs += pv;
                }
            l_lane[qb] += rs;
#pragma unroll
            for (int t4 = 0; t4 < 4; ++t4) {
                uint2 pk;
                pk.x = pk2(s[qb][t4][0], s[qb][t4][1]);
                pk.y = pk2(s[qb][t4][2], s[qb][t4][3]);
                *(uint2*)&Ps[w][(qb * 16 + l15) * PST + t4 * 16 + quad * 4] = pk;
            }
        }
        // no barrier: Ps[w] is wave-private

        // O^T += V^T · P
#pragma unroll
        for (int c2 = 0; c2 < 2; ++c2) {
            bf16x8 pf[2];
#pragma unroll
            for (int qb = 0; qb < 2; ++qb)
                pf[qb] = *(const bf16x8*)&Ps[w][(qb * 16 + l15) * PST + c2 * 32 + quad * 8];
#pragma unroll
            for (int db = 0; db < 4; ++db) {
                bf16x8 vf = *(const bf16x8*)&Vs[cur][(db * 16 + l15) * 64 + ((c2 * 4 + quad) * 8 ^ sw)];
#pragma unroll
                for (int qb = 0; qb < 2; ++qb)
                    oT[db][qb] = __builtin_amdgcn_mfma_f32_16x16x32_bf16(vf, pf[qb], oT[db][qb], 0, 0, 0);
            }
        }
    }

    // epilogue
#pragma unroll
    for (int qb = 0; qb < 2; ++qb) {
        float l = l_lane[qb];
        l += __shfl_xor(l, 16);
        l += __shfl_xor(l, 32);
        const float inv = 1.f / l;
        const int qrow = qt * 128 + w * 32 + qb * 16 + l15;
        const size_t ob = ((size_t)(b * NN + qrow) * HH + h) * DD;
#pragma unroll
        for (int db = 0; db < 4; ++db) {
            uint2 pk;
            pk.x = pk2(oT[db][qb][0] * inv, oT[db][qb][1] * inv);
            pk.y = pk2(oT[db][qb][2] * inv, oT[db][qb][3] * inv);
            *(uint2*)&att[ob + db * 16 + quad * 4] = pk;
        }
    }
}

// ---------------------------------------------------------------- launch
extern "C" void kernel_launch(void* const* d_in, const int* in_sizes, int n_in,
                              void* d_out, int out_size, void* d_ws, size_t ws_size,
                              hipStream_t stream) {
    const float* hs   = (const float*)d_in[0];
    const float* pos  = (const float*)d_in[1];
    const float* Wq   = (const float*)d_in[2];
    const float* bq   = (const float*)d_in[3];
    const float* Wk   = (const float*)d_in[4];
    const float* bk   = (const float*)d_in[5];
    const float* Wv   = (const float*)d_in[6];
    const float* bv   = (const float*)d_in[7];
    const float* Wpos = (const float*)d_in[8];
    const float* pbu  = (const float*)d_in[9];
    const float* pbv  = (const float*)d_in[10];
    const float* Wo   = (const float*)d_in[11];
    const float* bo   = (const float*)d_in[12];
    float* out = (float*)d_out;

    const size_t nHS = (size_t)MM * CC;
    const size_t nW  = (size_t)CC * CC;

    unsigned short* p = (unsigned short*)d_ws;
    unsigned short* hsb  = p;            p += nHS;
    unsigned short* posb = p;            p += nHS;
    unsigned short* wqb  = p;            p += nW;
    unsigned short* wkb  = p;            p += nW;
    unsigned short* wvb  = p;            p += nW;
    unsigned short* wpb  = p;            p += nW;
    unsigned short* wob  = p;            p += nW;
    unsigned short* qsb  = p;            p += nHS;
    unsigned short* kbf  = p;            p += nHS;
    unsigned short* kpb  = p;            p += nHS;
    unsigned short* vtb  = p;            p += nHS;
    float* cb = (float*)p;               p += (size_t)BB * HH * NN * 2;
    unsigned short* attb = hsb;          // alias: hsb dead after v-GEMM

    CastArgs ca;
    ca.src[0] = hs;   ca.dst[0] = hsb;  ca.n4[0] = (int)(nHS / 4);
    ca.src[1] = pos;  ca.dst[1] = posb; ca.n4[1] = (int)(nHS / 4);
    ca.src[2] = Wq;   ca.dst[2] = wqb;  ca.n4[2] = (int)(nW / 4);
    ca.src[3] = Wk;   ca.dst[3] = wkb;  ca.n4[3] = (int)(nW / 4);
    ca.src[4] = Wv;   ca.dst[4] = wvb;  ca.n4[4] = (int)(nW / 4);
    ca.src[5] = Wpos; ca.dst[5] = wpb;  ca.n4[5] = (int)(nW / 4);
    ca.src[6] = Wo;   ca.dst[6] = wob;  ca.n4[6] = (int)(nW / 4);
    dim3 cgrid((unsigned)(nHS / 4 / 256), 7);
    cast_all<<<cgrid, 256, 0, stream>>>(ca);

    dim3 ggrid(MM / 128, CC / 64);
    gemm_bt<1><<<ggrid, 256, 0, stream>>>(hsb, wqb, qsb, nullptr, bq);       // q * SC2E
    gemm_bt<0><<<ggrid, 256, 0, stream>>>(hsb, wkb, kbf, nullptr, bk);       // k
    gemm_bt<3><<<ggrid, 256, 0, stream>>>(hsb, wvb, vtb, nullptr, bv);       // v^T
    gemm_bt<4><<<ggrid, 256, 0, stream>>>(posb, wpb, kpb, kbf, nullptr);     // kp = p + k

    fuse_c<<<MM * HH / 4, 256, 0, stream>>>(kbf, kpb, pbu, pbv, cb);

    dim3 agrid(NN / 128, HH, BB);
    attn_kernel<<<agrid, 256, 0, stream>>>(qsb, kpb, vtb, cb, attb);

    gemm_bt<2><<<ggrid, 256, 0, stream>>>(attb, wob, out, nullptr, bo);      // out proj
}

// Round 6
// 278.731 us; speedup vs baseline: 1.1403x; 1.1403x over previous
//
#include <hip/hip_runtime.h>
#include <hip/hip_bf16.h>

// WhaleAttention: B=2, N=2048, C=1024, H=16, D=64, SCALE=1/8
// R6: revert R5 dbufs (regressed: occupancy loss > latency gain).
// - q/k/v/p GEMMs batched into ONE dispatch, m97 128x128 tile (16 MFMA/iter)
// - attn: 64-q blocks -> 1024 blocks = 4/CU (occupancy 20%->40%)
// - fuse_kpc: kp = k+p and c = u.k + v.p in one pass
// - 5 dispatches total.

typedef short bf16x8 __attribute__((ext_vector_type(8)));
typedef float f32x4 __attribute__((ext_vector_type(4)));

#define BB 2
#define NN 2048
#define CC 1024
#define HH 16
#define DD 64
#define MM (BB * NN)      // 4096 rows
#define SC2E 0.18033688f  // SCALE * log2(e)

__device__ __forceinline__ unsigned short f2bf(float f) {
    union { float f; unsigned int u; } x; x.f = f;
    unsigned int r = x.u + 0x7FFFu + ((x.u >> 16) & 1u);
    return (unsigned short)(r >> 16);
}

__device__ __forceinline__ float bf2f(unsigned short s) {
    union { unsigned int u; float f; } x; x.u = ((unsigned int)s) << 16;
    return x.f;
}

// packed f32x2 -> bf16x2 (v_cvt_pk_bf16_f32), low short = a
__device__ __forceinline__ unsigned int pk2(float a, float b) {
    __hip_bfloat162 h = __float22bfloat162_rn(make_float2(a, b));
    unsigned int u; __builtin_memcpy(&u, &h, 4); return u;
}

typedef __attribute__((address_space(1))) const unsigned int* gas1_t;
typedef __attribute__((address_space(3))) unsigned int* las3_t;

__device__ __forceinline__ void gload_lds16(const unsigned short* g, unsigned short* l) {
    __builtin_amdgcn_global_load_lds((gas1_t)g, (las3_t)l, 16, 0, 0);
}

// ---------------------------------------------------------------- cast kernel
struct CastArgs {
    const float* src[7];
    unsigned short* dst[7];
    int n4[7];
};
__global__ __launch_bounds__(256) void cast_all(CastArgs a) {
    const int seg = blockIdx.y;
    const int i = blockIdx.x * 256 + threadIdx.x;
    if (i >= a.n4[seg]) return;
    float4 v = ((const float4*)a.src[seg])[i];
    uint2 u;
    u.x = pk2(v.x, v.y);
    u.y = pk2(v.z, v.w);
    ((uint2*)a.dst[seg])[i] = u;
}

// ---------------------------------------------------------------- batched GEMM
// z in [0,4): q (bf16, (acc+bias)*SC2E), k (bf16, +bias), v (bf16 transposed
// (B,H,D,N), +bias), p (bf16, no bias). C[m][n] = sum_k A[m][k]*B[n][k].
// 128x128 tile, BK=32, 4 waves x (64x64) = 16 MFMA/wave-iter (m97 structure).
struct GemmBatch {
    const unsigned short* A[4];
    const unsigned short* B[4];
    unsigned short* out[4];
    const float* bias[4];
};
__global__ __launch_bounds__(256) void gemm_qkvp(GemmBatch g) {
    constexpr int K = CC;
    const int z = blockIdx.z;
    const unsigned short* __restrict__ A = g.A[z];
    const unsigned short* __restrict__ B = g.B[z];
    unsigned short* __restrict__ out = g.out[z];
    const float* __restrict__ bias = g.bias[z];

    __shared__ unsigned short As[128 * 32];
    __shared__ unsigned short Bs[128 * 32];
    const int t = threadIdx.x;
    const int w = t >> 6, lane = t & 63, l15 = lane & 15, quad = lane >> 4;
    const int m0 = blockIdx.x * 128, n0 = blockIdx.y * 128;
    const int wm = (w >> 1) * 64, wn = (w & 1) * 64;

    f32x4 acc[4][4];
#pragma unroll
    for (int i = 0; i < 4; ++i)
#pragma unroll
        for (int j = 0; j < 4; ++j)
#pragma unroll
            for (int r = 0; r < 4; ++r) acc[i][j][r] = 0.f;

    for (int kb = 0; kb < K; kb += 32) {
        __syncthreads();
#pragma unroll
        for (int j = 0; j < 2; ++j) {
            int id = j * 256 + t;
            int row = id >> 2, c4 = (id & 3) * 8;
            gload_lds16(&A[(size_t)(m0 + row) * K + kb + c4], &As[id * 8]);
            gload_lds16(&B[(size_t)(n0 + row) * K + kb + c4], &Bs[id * 8]);
        }
        __syncthreads();
        bf16x8 af[4], bfr[4];
#pragma unroll
        for (int i = 0; i < 4; ++i)
            af[i] = *(const bf16x8*)&As[(wm + i * 16 + l15) * 32 + quad * 8];
#pragma unroll
        for (int j = 0; j < 4; ++j)
            bfr[j] = *(const bf16x8*)&Bs[(wn + j * 16 + l15) * 32 + quad * 8];
#pragma unroll
        for (int i = 0; i < 4; ++i)
#pragma unroll
            for (int j = 0; j < 4; ++j)
                acc[i][j] = __builtin_amdgcn_mfma_f32_16x16x32_bf16(af[i], bfr[j], acc[i][j], 0, 0, 0);
    }

    // epilogue: C/D layout col = lane&15, row = quad*4 + reg
#pragma unroll
    for (int i = 0; i < 4; ++i) {
#pragma unroll
        for (int j = 0; j < 4; ++j) {
            const int col = n0 + wn + j * 16 + l15;
            const int row_base = m0 + wm + i * 16 + quad * 4;
            if (z == 0) {        // q: (acc + bq) * SC2E
                const float bc = bias[col];
#pragma unroll
                for (int r = 0; r < 4; ++r)
                    out[(size_t)(row_base + r) * CC + col] = f2bf((acc[i][j][r] + bc) * SC2E);
            } else if (z == 1) { // k: acc + bk
                const float bc = bias[col];
#pragma unroll
                for (int r = 0; r < 4; ++r)
                    out[(size_t)(row_base + r) * CC + col] = f2bf(acc[i][j][r] + bc);
            } else if (z == 2) { // v: transposed (B,H,D,N), acc + bv
                const float bc = bias[col];
                const int b = row_base >> 11, nseq = row_base & 2047;
                const int hh = col >> 6, dd = col & 63;
                union { unsigned short s[4]; uint2 u; } pk;
#pragma unroll
                for (int r = 0; r < 4; ++r) pk.s[r] = f2bf(acc[i][j][r] + bc);
                size_t idx = ((size_t)(b * HH + hh) * DD + dd) * NN + nseq;
                *(uint2*)&out[idx] = pk.u;
            } else {             // p: plain
#pragma unroll
                for (int r = 0; r < 4; ++r)
                    out[(size_t)(row_base + r) * CC + col] = f2bf(acc[i][j][r]);
            }
        }
    }
}

// ---------------------------------------------------------------- out GEMM
// out fp32 = A·B^T + bo.  128x128 tile, same structure.
__global__ __launch_bounds__(256) void gemm_out(const unsigned short* __restrict__ A,
                                                const unsigned short* __restrict__ B,
                                                float* __restrict__ out,
                                                const float* __restrict__ bias) {
    constexpr int K = CC;
    __shared__ unsigned short As[128 * 32];
    __shared__ unsigned short Bs[128 * 32];
    const int t = threadIdx.x;
    const int w = t >> 6, lane = t & 63, l15 = lane & 15, quad = lane >> 4;
    const int m0 = blockIdx.x * 128, n0 = blockIdx.y * 128;
    const int wm = (w >> 1) * 64, wn = (w & 1) * 64;

    f32x4 acc[4][4];
#pragma unroll
    for (int i = 0; i < 4; ++i)
#pragma unroll
        for (int j = 0; j < 4; ++j)
#pragma unroll
            for (int r = 0; r < 4; ++r) acc[i][j][r] = 0.f;

    for (int kb = 0; kb < K; kb += 32) {
        __syncthreads();
#pragma unroll
        for (int j = 0; j < 2; ++j) {
            int id = j * 256 + t;
            int row = id >> 2, c4 = (id & 3) * 8;
            gload_lds16(&A[(size_t)(m0 + row) * K + kb + c4], &As[id * 8]);
            gload_lds16(&B[(size_t)(n0 + row) * K + kb + c4], &Bs[id * 8]);
        }
        __syncthreads();
        bf16x8 af[4], bfr[4];
#pragma unroll
        for (int i = 0; i < 4; ++i)
            af[i] = *(const bf16x8*)&As[(wm + i * 16 + l15) * 32 + quad * 8];
#pragma unroll
        for (int j = 0; j < 4; ++j)
            bfr[j] = *(const bf16x8*)&Bs[(wn + j * 16 + l15) * 32 + quad * 8];
#pragma unroll
        for (int i = 0; i < 4; ++i)
#pragma unroll
            for (int j = 0; j < 4; ++j)
                acc[i][j] = __builtin_amdgcn_mfma_f32_16x16x32_bf16(af[i], bfr[j], acc[i][j], 0, 0, 0);
    }

#pragma unroll
    for (int i = 0; i < 4; ++i) {
#pragma unroll
        for (int j = 0; j < 4; ++j) {
            const int col = n0 + wn + j * 16 + l15;
            const int row_base = m0 + wm + i * 16 + quad * 4;
            const float bc = bias[col];
#pragma unroll
            for (int r = 0; r < 4; ++r)
                out[(size_t)(row_base + r) * CC + col] = acc[i][j][r] + bc;
        }
    }
}

// ---------------------------------------------------------------- fuse kp + c
// One wave per (row, h): kp = k + p (bf16) and c = SC2E*(u·k + v·p) (fp32).
__global__ __launch_bounds__(256) void fuse_kpc(const unsigned short* __restrict__ k,
                                                const unsigned short* __restrict__ pp,
                                                const float* __restrict__ pbu,
                                                const float* __restrict__ pbv,
                                                unsigned short* __restrict__ kp,
                                                float* __restrict__ c) {
    const int gw = (blockIdx.x * 256 + threadIdx.x) >> 6;
    const int lane = threadIdx.x & 63;
    const int row = gw >> 4, h = gw & 15;          // row = b*N + n
    const size_t off = (size_t)row * CC + h * 64 + lane;
    const float kv = bf2f(k[off]), pv = bf2f(pp[off]);
    kp[off] = f2bf(kv + pv);
    float val = pbu[h * 64 + lane] * kv + pbv[h * 64 + lane] * pv;
#pragma unroll
    for (int o = 1; o < 64; o <<= 1) val += __shfl_xor(val, o);
    if (lane == 0) {
        const int b = row >> 11, n = row & 2047;
        c[((size_t)(b * HH + h)) * NN + n] = val * SC2E;
    }
}

// ---------------------------------------------------------------- attention
// Block: (qt,h,b) -> 64 Q rows; 4 waves x 16 Q. 1024 blocks = 4/CU.
//   S^T[key][q] = KP·Q^T, accumulator initialized with c[key]
//   P = exp2(S) (fixed base), per-wave LDS round-trip -> B-frags
//   O^T[d][q] = V^T·P; final O /= l.
#define PST 80
__global__ __launch_bounds__(256) void attn_kernel(const unsigned short* __restrict__ q,
                                                   const unsigned short* __restrict__ kp,
                                                   const unsigned short* __restrict__ vt,
                                                   const float* __restrict__ cb,
                                                   unsigned short* __restrict__ att) {
    __shared__ unsigned short Ks[64 * 64];
    __shared__ unsigned short Vs[64 * 64];
    __shared__ unsigned short Ps[4][16 * PST];

    const int t = threadIdx.x;
    const int w = t >> 6, lane = t & 63, l15 = lane & 15, quad = lane >> 4;
    const int qt = blockIdx.x, h = blockIdx.y, b = blockIdx.z;
    const int sw = (l15 & 7) * 8;

    // Q fragments (B-layout: n = lane&15 = q, k = quad*8+j)
    const int qrow = qt * 64 + w * 16 + l15;
    const size_t qoff = ((size_t)(b * NN + qrow) * HH + h) * DD;
    bf16x8 qf[2];
#pragma unroll
    for (int c2 = 0; c2 < 2; ++c2)
        qf[c2] = *(const bf16x8*)&q[qoff + c2 * 32 + quad * 8];

    f32x4 oT[4];
    float l_lane = 0.f;
#pragma unroll
    for (int db = 0; db < 4; ++db)
#pragma unroll
        for (int r = 0; r < 4; ++r) oT[db][r] = 0.f;

    const size_t kbase = (size_t)b * NN * CC + (size_t)h * DD;
    const size_t vbase = (size_t)(b * HH + h) * DD * NN;
    const size_t cbase = (size_t)(b * HH + h) * NN;

    for (int kt = 0; kt < NN / 64; ++kt) {
        __syncthreads();
#pragma unroll
        for (int j = 0; j < 2; ++j) {
            int id = j * 256 + t, row = id >> 3, c8 = id & 7;
            int gc = (c8 ^ (row & 7)) * 8;
            gload_lds16(&kp[kbase + (size_t)(kt * 64 + row) * CC + gc], &Ks[id * 8]);
            gload_lds16(&vt[vbase + (size_t)row * NN + kt * 64 + gc], &Vs[id * 8]);
        }
        __syncthreads();

        // S^T with c-initialized accumulators
        f32x4 s[4];
#pragma unroll
        for (int t4 = 0; t4 < 4; ++t4)
            s[t4] = *(const f32x4*)&cb[cbase + kt * 64 + t4 * 16 + quad * 4];
#pragma unroll
        for (int t4 = 0; t4 < 4; ++t4) {
            const int row = t4 * 16 + l15;
#pragma unroll
            for (int c2 = 0; c2 < 2; ++c2) {
                bf16x8 kf = *(const bf16x8*)&Ks[row * 64 + ((c2 * 4 + quad) * 8 ^ sw)];
                s[t4] = __builtin_amdgcn_mfma_f32_16x16x32_bf16(kf, qf[c2], s[t4], 0, 0, 0);
            }
        }

        // fixed-base exp2 softmax; l reduced at end
        float rs = 0.f;
#pragma unroll
        for (int t4 = 0; t4 < 4; ++t4)
#pragma unroll
            for (int r = 0; r < 4; ++r) {
                float pv = exp2f(s[t4][r]);
                s[t4][r] = pv;
                rs += pv;
            }
        l_lane += rs;
#pragma unroll
        for (int t4 = 0; t4 < 4; ++t4) {
            uint2 pk;
            pk.x = pk2(s[t4][0], s[t4][1]);
            pk.y = pk2(s[t4][2], s[t4][3]);
            *(uint2*)&Ps[w][l15 * PST + t4 * 16 + quad * 4] = pk;
        }
        // no barrier: Ps[w] is wave-private

        // O^T += V^T · P
#pragma unroll
        for (int c2 = 0; c2 < 2; ++c2) {
            bf16x8 pf = *(const bf16x8*)&Ps[w][l15 * PST + c2 * 32 + quad * 8];
#pragma unroll
            for (int db = 0; db < 4; ++db) {
                bf16x8 vf = *(const bf16x8*)&Vs[(db * 16 + l15) * 64 + ((c2 * 4 + quad) * 8 ^ sw)];
                oT[db] = __builtin_amdgcn_mfma_f32_16x16x32_bf16(vf, pf, oT[db], 0, 0, 0);
            }
        }
    }

    // epilogue
    float l = l_lane;
    l += __shfl_xor(l, 16);
    l += __shfl_xor(l, 32);
    const float inv = 1.f / l;
    const size_t ob = ((size_t)(b * NN + qrow) * HH + h) * DD;
#pragma unroll
    for (int db = 0; db < 4; ++db) {
        uint2 pk;
        pk.x = pk2(oT[db][0] * inv, oT[db][1] * inv);
        pk.y = pk2(oT[db][2] * inv, oT[db][3] * inv);
        *(uint2*)&att[ob + db * 16 + quad * 4] = pk;
    }
}

// ---------------------------------------------------------------- launch
extern "C" void kernel_launch(void* const* d_in, const int* in_sizes, int n_in,
                              void* d_out, int out_size, void* d_ws, size_t ws_size,
                              hipStream_t stream) {
    const float* hs   = (const float*)d_in[0];
    const float* pos  = (const float*)d_in[1];
    const float* Wq   = (const float*)d_in[2];
    const float* bq   = (const float*)d_in[3];
    const float* Wk   = (const float*)d_in[4];
    const float* bk   = (const float*)d_in[5];
    const float* Wv   = (const float*)d_in[6];
    const float* bv   = (const float*)d_in[7];
    const float* Wpos = (const float*)d_in[8];
    const float* pbu  = (const float*)d_in[9];
    const float* pbv  = (const float*)d_in[10];
    const float* Wo   = (const float*)d_in[11];
    const float* bo   = (const float*)d_in[12];
    float* out = (float*)d_out;

    const size_t nHS = (size_t)MM * CC;
    const size_t nW  = (size_t)CC * CC;

    unsigned short* p = (unsigned short*)d_ws;
    unsigned short* hsb  = p;            p += nHS;
    unsigned short* posb = p;            p += nHS;
    unsigned short* wqb  = p;            p += nW;
    unsigned short* wkb  = p;            p += nW;
    unsigned short* wvb  = p;            p += nW;
    unsigned short* wpb  = p;            p += nW;
    unsigned short* wob  = p;            p += nW;
    unsigned short* qsb  = p;            p += nHS;
    unsigned short* kbf  = p;            p += nHS;
    unsigned short* pbf  = p;            p += nHS;
    unsigned short* kpb  = p;            p += nHS;
    unsigned short* vtb  = p;            p += nHS;
    float* cb = (float*)p;               p += (size_t)BB * HH * NN * 2;
    unsigned short* attb = hsb;          // alias: hsb dead after gemm_qkvp

    CastArgs ca;
    ca.src[0] = hs;   ca.dst[0] = hsb;  ca.n4[0] = (int)(nHS / 4);
    ca.src[1] = pos;  ca.dst[1] = posb; ca.n4[1] = (int)(nHS / 4);
    ca.src[2] = Wq;   ca.dst[2] = wqb;  ca.n4[2] = (int)(nW / 4);
    ca.src[3] = Wk;   ca.dst[3] = wkb;  ca.n4[3] = (int)(nW / 4);
    ca.src[4] = Wv;   ca.dst[4] = wvb;  ca.n4[4] = (int)(nW / 4);
    ca.src[5] = Wpos; ca.dst[5] = wpb;  ca.n4[5] = (int)(nW / 4);
    ca.src[6] = Wo;   ca.dst[6] = wob;  ca.n4[6] = (int)(nW / 4);
    dim3 cgrid((unsigned)(nHS / 4 / 256), 7);
    cast_all<<<cgrid, 256, 0, stream>>>(ca);

    GemmBatch gb;
    gb.A[0] = hsb;  gb.B[0] = wqb; gb.out[0] = qsb; gb.bias[0] = bq;
    gb.A[1] = hsb;  gb.B[1] = wkb; gb.out[1] = kbf; gb.bias[1] = bk;
    gb.A[2] = hsb;  gb.B[2] = wvb; gb.out[2] = vtb; gb.bias[2] = bv;
    gb.A[3] = posb; gb.B[3] = wpb; gb.out[3] = pbf; gb.bias[3] = nullptr;
    dim3 ggrid(MM / 128, CC / 128, 4);
    gemm_qkvp<<<ggrid, 256, 0, stream>>>(gb);

    fuse_kpc<<<MM * HH / 4, 256, 0, stream>>>(kbf, pbf, pbu, pbv, kpb, cb);

    dim3 agrid(NN / 64, HH, BB);
    attn_kernel<<<agrid, 256, 0, stream>>>(qsb, kpb, vtb, cb, attb);

    dim3 ogrid(MM / 128, CC / 128);
    gemm_out<<<ogrid, 256, 0, stream>>>(attb, wob, out, bo);
}